// Round 6
// baseline (708.617 us; speedup 1.0000x reference)
//
#include <hip/hip_runtime.h>
#include <hip/hip_bf16.h>

// ---------------------------------------------------------------------------
// DeltaNet forward, round 6:
//  - delta_attn_add fused INTO delta_chain_mfma (attn@u2 via 3 extra MFMAs on
//    the o1-waves using the already-built uh/ul fragments); u2 never written
//    to global; chain writes final delta directly.
//  - o1-waves read only Shi (drop Slo): -16 b128 LDS reads/chunk.
//  - conv4_silu x3 + prep_qkv fused into one conv_prep kernel (-96MB traffic,
//    -3 launches).
//  - mlp hidden activations stored bf16 (-32MB traffic).
// ---------------------------------------------------------------------------

#define DEVI __device__ __forceinline__
typedef unsigned int u32;
typedef unsigned short ushort_t;
typedef __attribute__((ext_vector_type(8))) short short8;
typedef __attribute__((ext_vector_type(4))) float floatx4;

constexpr int Ls = 2048, NH = 4;
constexpr int NCh = 64;

// workspace offsets (floats)
constexpr size_t off_xq   = 0;         // x@Wq (token-major)
constexpr size_t off_xk   = 4194304;   // x@Wk -> (dead) -> w1_t (bf16)
constexpr size_t off_xv   = 8388608;   // x@Wv -> u (chunk_prep) -> (dead) -> o_bf
constexpr size_t off_q    = 12582912;  // qn -> delta (chain output)
constexpr size_t off_k    = 16777216;  // kn
constexpr size_t off_v    = 20971520;  // v (alive to the end)
constexpr size_t off_beta = 25165824;  // beta -> Wo_t (bf16, spans into attn)
constexpr size_t off_attn = 25182208;  // attn (dead after chain)
constexpr size_t off_firs = 25706496;  // x_bf -> {wn_bf, q_bf} -> firs f32
constexpr size_t off_firl = 29900800;  // W*_t -> knT_bf -> firl f32
constexpr size_t off_gin  = 34095104;  // kb (f32, conv_prep) -> gin_bf
constexpr size_t off_mlph = 38420480;  // vb (f32, conv_prep) -> mlph_bf
constexpr size_t off_gates= 46809088;  // gates

DEVI float sigmoidf_(float x) { return 1.f / (1.f + expf(-x)); }
DEVI float siluf_(float x) { return x / (1.f + expf(-x)); }
DEVI float geluf_(float x) { return 0.5f * x * (1.f + erff(x * 0.7071067811865476f)); }
DEVI ushort_t f2bf(float f) {
  union { float f; u32 u; } c{f};
  u32 r = (c.u + 0x7fffu + ((c.u >> 16) & 1u)) >> 16;
  return (ushort_t)r;
}
DEVI float bf2f(ushort_t h) {
  union { u32 u; float f; } c; c.u = ((u32)h) << 16; return c.f;
}
DEVI void cvt8(float4 a, float4 b, short8& hi, short8& lo) {
  float f[8] = {a.x,a.y,a.z,a.w,b.x,b.y,b.z,b.w};
#pragma unroll
  for (int j = 0; j < 8; ++j) {
    ushort_t h = f2bf(f[j]);
    hi[j] = (short)h;
    lo[j] = (short)f2bf(f[j] - bf2f(h));
  }
}
DEVI void async16(const void* g, void* l) {
  __builtin_amdgcn_global_load_lds(
      (const u32 __attribute__((address_space(1)))*)g,
      (u32 __attribute__((address_space(3)))*)l, 16, 0, 0);
}

// ---------------- f32 -> bf16 ----------------------------------------------
__global__ __launch_bounds__(256) void to_bf16(
    const float* __restrict__ in, ushort_t* __restrict__ out, int n)
{
  int i = (blockIdx.x * 256 + threadIdx.x) * 8;
  if (i >= n) return;
  float4 a = *(const float4*)(in + i);
  float4 b = *(const float4*)(in + i + 4);
  ushort_t o[8] = { f2bf(a.x), f2bf(a.y), f2bf(a.z), f2bf(a.w),
                    f2bf(b.x), f2bf(b.y), f2bf(b.z), f2bf(b.w) };
  *(uint4*)(out + i) = *(uint4*)o;
}

// ---------------- f32 [K][N] -> bf16 [N][K] --------------------------------
__global__ __launch_bounds__(256) void convT(
    const float* __restrict__ W, ushort_t* __restrict__ out, int Kq, int Nq)
{
  __shared__ ushort_t tile[32][33];
  int n0 = blockIdx.x * 32, k0 = blockIdx.y * 32;
  int tx = threadIdx.x & 31, ty = threadIdx.x >> 5;
#pragma unroll
  for (int r = 0; r < 32; r += 8)
    tile[ty + r][tx] = f2bf(W[(size_t)(k0 + ty + r) * Nq + n0 + tx]);
  __syncthreads();
#pragma unroll
  for (int r = 0; r < 32; r += 8)
    out[(size_t)(n0 + ty + r) * Kq + k0 + tx] = tile[tx][ty + r];
}

// ---------------- bf16 MFMA GEMM (outbf: write bf16 C) ---------------------
__global__ __launch_bounds__(256) void gemm_bf16(
    const ushort_t* __restrict__ A, const ushort_t* __restrict__ Bt,
    float* __restrict__ C, int Nq, int Kq,
    const float* __restrict__ bias, int act, int outbf)
{
  __shared__ ushort_t As[128 * 32];
  __shared__ ushort_t Bs[128 * 32];
  int t = threadIdx.x;
  int w = t >> 6, lane = t & 63;
  int m0 = blockIdx.y * 128, n0 = blockIdx.x * 128;
  floatx4 acc[4][4];
#pragma unroll
  for (int i = 0; i < 4; ++i)
#pragma unroll
    for (int j = 0; j < 4; ++j)
#pragma unroll
      for (int r = 0; r < 4; ++r) acc[i][j][r] = 0.f;

  int lrow = lane >> 2, lk8 = (lane & 3) * 8;
  for (int kt = 0; kt < Kq; kt += 32) {
#pragma unroll
    for (int r = 0; r < 2; ++r) {
      int seg = w * 2 + r;
      int row = seg * 16 + lrow;
      async16(A  + (size_t)(m0 + row) * Kq + kt + lk8, &As[seg * 512]);
      async16(Bt + (size_t)(n0 + row) * Kq + kt + lk8, &Bs[seg * 512]);
    }
    __syncthreads();
    short8 af[4], bf[4];
#pragma unroll
    for (int i = 0; i < 4; ++i) {
      int row = (w >> 1) * 64 + i * 16 + (lane & 15);
      af[i] = *(const short8*)&As[row * 32 + (lane >> 4) * 8];
    }
#pragma unroll
    for (int j = 0; j < 4; ++j) {
      int col = (w & 1) * 64 + j * 16 + (lane & 15);
      bf[j] = *(const short8*)&Bs[col * 32 + (lane >> 4) * 8];
    }
#pragma unroll
    for (int i = 0; i < 4; ++i)
#pragma unroll
      for (int j = 0; j < 4; ++j)
        acc[i][j] = __builtin_amdgcn_mfma_f32_16x16x32_bf16(af[i], bf[j], acc[i][j], 0, 0, 0);
    __syncthreads();
  }
#pragma unroll
  for (int i = 0; i < 4; ++i) {
    int rbase = m0 + (w >> 1) * 64 + i * 16 + ((lane >> 4) << 2);
#pragma unroll
    for (int j = 0; j < 4; ++j) {
      int col = n0 + (w & 1) * 64 + j * 16 + (lane & 15);
      float bv = act ? bias[col] : 0.f;
#pragma unroll
      for (int r = 0; r < 4; ++r) {
        float v = acc[i][j][r];
        if (act) v = geluf_(v + bv);
        if (outbf) ((ushort_t*)C)[(size_t)(rbase + r) * Nq + col] = f2bf(v);
        else       C[(size_t)(rbase + r) * Nq + col] = v;
      }
    }
  }
}

// ---------------- beta = sigmoid(x @ Wb) -----------------------------------
__global__ __launch_bounds__(256) void beta_sigmoid(
    const float* __restrict__ x, const float* __restrict__ Wb,
    float* __restrict__ beta)
{
  int mtok = blockIdx.x, t = threadIdx.x;
  int b = mtok >> 11, l = mtok & 2047;
  float a0 = 0, a1 = 0, a2 = 0, a3 = 0;
  for (int k = t; k < 1024; k += 256) {
    float xv = x[(size_t)mtok * 1024 + k];
    float4 w4 = *(const float4*)(Wb + k * 4);
    a0 = fmaf(xv, w4.x, a0); a1 = fmaf(xv, w4.y, a1);
    a2 = fmaf(xv, w4.z, a2); a3 = fmaf(xv, w4.w, a3);
  }
#pragma unroll
  for (int off = 32; off; off >>= 1) {
    a0 += __shfl_down(a0, off); a1 += __shfl_down(a1, off);
    a2 += __shfl_down(a2, off); a3 += __shfl_down(a3, off);
  }
  __shared__ float red[4][4];
  int w = t >> 6;
  if ((t & 63) == 0) { red[w][0] = a0; red[w][1] = a1; red[w][2] = a2; red[w][3] = a3; }
  __syncthreads();
  if (t < 4) {
    float s = red[0][t] + red[1][t] + red[2][t] + red[3][t];
    beta[((size_t)(b * NH + t)) * Ls + l] = sigmoidf_(s);
  }
}

// ------- fused: conv4+silu (q,k,v) + l2norm + beta products ----------------
// one block per (bh,l); outputs head-major qn, kn, kb, vb, v.
__global__ __launch_bounds__(256) void conv_prep(
    const float* __restrict__ xq, const float* __restrict__ xk,
    const float* __restrict__ xv, const float* __restrict__ wq,
    const float* __restrict__ wk, const float* __restrict__ wv,
    const float* __restrict__ beta_g,
    float* __restrict__ qn, float* __restrict__ kn,
    float* __restrict__ kb, float* __restrict__ vb,
    float* __restrict__ v_out)
{
  int i = blockIdx.x;              // bh*Ls + l
  int t = threadIdx.x;
  int l = i & 2047, bh = i >> 11;
  int b = bh >> 2, h = bh & 3;
  int c = h * 256 + t;
  const float* xqp = xq + ((size_t)b * Ls) * 1024 + c;
  const float* xkp = xk + ((size_t)b * Ls) * 1024 + c;
  const float* xvp = xv + ((size_t)b * Ls) * 1024 + c;
  float4 wq4 = *(const float4*)(wq + c * 4);
  float4 wk4 = *(const float4*)(wk + c * 4);
  float4 wv4 = *(const float4*)(wv + c * 4);
  float qw[4] = {wq4.x, wq4.y, wq4.z, wq4.w};
  float kw[4] = {wk4.x, wk4.y, wk4.z, wk4.w};
  float vw[4] = {wv4.x, wv4.y, wv4.z, wv4.w};
  float aq = 0.f, ak = 0.f, av = 0.f;
#pragma unroll
  for (int j = 0; j < 4; ++j) {
    int ls = l - 3 + j;
    if (ls >= 0) {
      float xa = xqp[(size_t)ls * 1024];
      float xb = xkp[(size_t)ls * 1024];
      float xc = xvp[(size_t)ls * 1024];
      aq = fmaf(qw[j], xa, aq);
      ak = fmaf(kw[j], xb, ak);
      av = fmaf(vw[j], xc, av);
    }
  }
  float qv = siluf_(aq), kv = siluf_(ak), vv = siluf_(av);
  float sq = qv * qv, sk = kv * kv;
#pragma unroll
  for (int off = 32; off; off >>= 1) {
    sq += __shfl_down(sq, off);
    sk += __shfl_down(sk, off);
  }
  __shared__ float rq_[4], rk_[4];
  int w = t >> 6;
  if ((t & 63) == 0) { rq_[w] = sq; rk_[w] = sk; }
  __syncthreads();
  sq = rq_[0] + rq_[1] + rq_[2] + rq_[3];
  sk = rk_[0] + rk_[1] + rk_[2] + rk_[3];
  float rq = rsqrtf(sq + 1e-6f), rk = rsqrtf(sk + 1e-6f);
  float bt = beta_g[i];
  size_t base = (size_t)i * 256 + t;
  qn[base] = qv * rq;
  kn[base] = kv * rk;
  kb[base] = kv * rk * bt;
  vb[base] = vv * bt;
  v_out[base] = vv;
}

// ------- per (b,h,chunk) MFMA: Gram, substitution, w/u applies -------------
__global__ __launch_bounds__(256) void chunk_prep(
    const float* __restrict__ kb, const float* __restrict__ kn,
    const float* __restrict__ qn, const float* __restrict__ vb,
    float* __restrict__ attn_g, float* __restrict__ u_out,
    ushort_t* __restrict__ wn_bf, ushort_t* __restrict__ q_bf,
    ushort_t* __restrict__ knT_bf)
{
  __shared__ float Am[32][33];
  __shared__ float Tm[32][36];
  __shared__ ushort_t KT_hi[256][40];
  __shared__ ushort_t KT_lo[256][40];
  int t = threadIdx.x;
  int cc = blockIdx.x & 63, bh = blockIdx.x >> 6;
  size_t gbase = ((size_t)bh * Ls + cc * 32) * 256;
  int wv = t >> 6, lane = t & 63;
  int l16 = lane & 15, quad = lane >> 4;
  int mi = wv >> 1, ni = wv & 1;

  floatx4 Aacc = {0.f,0.f,0.f,0.f}, Qacc = {0.f,0.f,0.f,0.f};
  {
    int mrow = mi * 16 + l16, nrow = ni * 16 + l16;
    const float* kbp = kb + gbase + (size_t)mrow * 256;
    const float* qnp = qn + gbase + (size_t)mrow * 256;
    const float* knp = kn + gbase + (size_t)nrow * 256;
#pragma unroll
    for (int ks = 0; ks < 8; ++ks) {
      int koff = ks * 32 + quad * 8;
      short8 kbh, kbl, qnh, qnl, knh, knl;
      cvt8(*(const float4*)(kbp + koff), *(const float4*)(kbp + koff + 4), kbh, kbl);
      cvt8(*(const float4*)(qnp + koff), *(const float4*)(qnp + koff + 4), qnh, qnl);
      cvt8(*(const float4*)(knp + koff), *(const float4*)(knp + koff + 4), knh, knl);
      Aacc = __builtin_amdgcn_mfma_f32_16x16x32_bf16(kbh, knh, Aacc, 0, 0, 0);
      Aacc = __builtin_amdgcn_mfma_f32_16x16x32_bf16(kbh, knl, Aacc, 0, 0, 0);
      Aacc = __builtin_amdgcn_mfma_f32_16x16x32_bf16(kbl, knh, Aacc, 0, 0, 0);
      Qacc = __builtin_amdgcn_mfma_f32_16x16x32_bf16(qnh, knh, Qacc, 0, 0, 0);
      Qacc = __builtin_amdgcn_mfma_f32_16x16x32_bf16(qnh, knl, Qacc, 0, 0, 0);
      Qacc = __builtin_amdgcn_mfma_f32_16x16x32_bf16(qnl, knh, Qacc, 0, 0, 0);
      if (ni == 0)
        *(uint4*)(q_bf + gbase + (size_t)mrow * 256 + koff) = *(uint4*)&qnh;
    }
  }
  float* ag = attn_g + ((size_t)bh * 64 + cc) * 1024;
#pragma unroll
  for (int r = 0; r < 4; ++r) {
    int row = mi * 16 + quad * 4 + r, col = ni * 16 + l16;
    Am[row][col] = (col < row) ? Aacc[r] : 0.f;
    ag[row * 32 + col] = (col <= row) ? Qacc[r] : 0.f;
  }
  __syncthreads();

  if (wv == 0) {
    if (t < 32) {
#pragma unroll
      for (int i = 0; i < 32; ++i) Tm[i][t] = (i == t) ? 1.f : 0.f;
      for (int i2 = 1; i2 < 32; ++i2) {
        if (t < i2) {
          float s = 0.f;
          for (int m2 = t; m2 < i2; ++m2) s = fmaf(Am[i2][m2], Tm[m2][t], s);
          Tm[i2][t] = -s;
        }
      }
    }
  } else {
    int base = t - 64;
#pragma unroll
    for (int pass = 0; pass < 2; ++pass) {
      int d = base + pass * 192;
      if (d < 256) {
        u32 hp[16], lp[16], kp2[16];
#pragma unroll
        for (int m2 = 0; m2 < 16; ++m2) {
          float f0 = kb[gbase + (size_t)(2 * m2) * 256 + d];
          float f1 = kb[gbase + (size_t)(2 * m2 + 1) * 256 + d];
          ushort_t h0 = f2bf(f0), h1 = f2bf(f1);
          hp[m2] = (u32)h0 | ((u32)h1 << 16);
          lp[m2] = (u32)f2bf(f0 - bf2f(h0)) | ((u32)f2bf(f1 - bf2f(h1)) << 16);
          float g0 = kn[gbase + (size_t)(2 * m2) * 256 + d];
          float g1 = kn[gbase + (size_t)(2 * m2 + 1) * 256 + d];
          kp2[m2] = (u32)f2bf(g0) | ((u32)f2bf(g1) << 16);
        }
#pragma unroll
        for (int q2 = 0; q2 < 4; ++q2) {
          *(uint4*)&KT_hi[d][q2 * 8] = *(uint4*)&hp[q2 * 4];
          *(uint4*)&KT_lo[d][q2 * 8] = *(uint4*)&lp[q2 * 4];
          *(uint4*)(knT_bf + gbase + (size_t)d * 32 + q2 * 8) = *(uint4*)&kp2[q2 * 4];
        }
      }
    }
  }
  __syncthreads();

  int lt = wv & 1, dgrp = wv >> 1;
  short8 Th, Tl;
  {
    int lrow = lt * 16 + l16;
    cvt8(*(const float4*)&Tm[lrow][quad * 8],
         *(const float4*)&Tm[lrow][quad * 8 + 4], Th, Tl);
  }
#pragma unroll
  for (int j = 0; j < 8; ++j) {
    int dt = dgrp * 8 + j;
    short8 Bh = *(const short8*)&KT_hi[dt * 16 + l16][quad * 8];
    short8 Bl = *(const short8*)&KT_lo[dt * 16 + l16][quad * 8];
    floatx4 acc = {0.f,0.f,0.f,0.f};
    acc = __builtin_amdgcn_mfma_f32_16x16x32_bf16(Th, Bh, acc, 0, 0, 0);
    acc = __builtin_amdgcn_mfma_f32_16x16x32_bf16(Th, Bl, acc, 0, 0, 0);
    acc = __builtin_amdgcn_mfma_f32_16x16x32_bf16(Tl, Bh, acc, 0, 0, 0);
#pragma unroll
    for (int r = 0; r < 4; ++r) {
      int row = lt * 16 + quad * 4 + r;
      wn_bf[gbase + (size_t)row * 256 + dt * 16 + l16] = f2bf(-acc[r]);
    }
  }
  __syncthreads();

  {
    int d = t;
    u32 hp[16], lp[16];
#pragma unroll
    for (int m2 = 0; m2 < 16; ++m2) {
      float f0 = vb[gbase + (size_t)(2 * m2) * 256 + d];
      float f1 = vb[gbase + (size_t)(2 * m2 + 1) * 256 + d];
      ushort_t h0 = f2bf(f0), h1 = f2bf(f1);
      hp[m2] = (u32)h0 | ((u32)h1 << 16);
      lp[m2] = (u32)f2bf(f0 - bf2f(h0)) | ((u32)f2bf(f1 - bf2f(h1)) << 16);
    }
#pragma unroll
    for (int q2 = 0; q2 < 4; ++q2) {
      *(uint4*)&KT_hi[d][q2 * 8] = *(uint4*)&hp[q2 * 4];
      *(uint4*)&KT_lo[d][q2 * 8] = *(uint4*)&lp[q2 * 4];
    }
  }
  __syncthreads();

#pragma unroll
  for (int j = 0; j < 8; ++j) {
    int dt = dgrp * 8 + j;
    short8 Bh = *(const short8*)&KT_hi[dt * 16 + l16][quad * 8];
    short8 Bl = *(const short8*)&KT_lo[dt * 16 + l16][quad * 8];
    floatx4 acc = {0.f,0.f,0.f,0.f};
    acc = __builtin_amdgcn_mfma_f32_16x16x32_bf16(Th, Bh, acc, 0, 0, 0);
    acc = __builtin_amdgcn_mfma_f32_16x16x32_bf16(Th, Bl, acc, 0, 0, 0);
    acc = __builtin_amdgcn_mfma_f32_16x16x32_bf16(Tl, Bh, acc, 0, 0, 0);
#pragma unroll
    for (int r = 0; r < 4; ++r) {
      int row = lt * 16 + quad * 4 + r;
      u_out[gbase + (size_t)row * 256 + dt * 16 + l16] = acc[r];
    }
  }
}

// ------- MFMA serial chunk scan, attn@u2 fused, delta written directly -----
__global__ __launch_bounds__(256, 1) void delta_chain_mfma(
    const ushort_t* __restrict__ wn_bf, const ushort_t* __restrict__ q_bf,
    const ushort_t* __restrict__ knT_bf, const float* __restrict__ attn_g,
    const float* __restrict__ u_g, float* __restrict__ delta_g)
{
  __shared__ ushort_t Shi[16][264];
  __shared__ ushort_t Slo[16][264];
  __shared__ float u2L[32][17];
  int t = threadIdx.x;
  int bh = blockIdx.x & 7, g = blockIdx.x >> 3;
  int b = bh >> 2, h = bh & 3;
  int wv = t >> 6, lane = t & 63;
  int lquad = lane >> 4, l16 = lane & 15;
  int j0 = g * 16;
  const ushort_t* wp = wn_bf + (size_t)bh * Ls * 256;
  const ushort_t* qp = q_bf  + (size_t)bh * Ls * 256;
  const ushort_t* kp = knT_bf + (size_t)bh * Ls * 256;
  const float* up = u_g + (size_t)bh * Ls * 256;
  const float* atp = attn_g + (size_t)bh * 64 * 1024;
  int Mt = wv & 1;
  bool isU = (wv < 2);
  floatx4 Sacc[4], SaccL[4];
#pragma unroll
  for (int i = 0; i < 4; ++i)
#pragma unroll
    for (int r = 0; r < 4; ++r) { Sacc[i][r] = 0.f; SaccL[i][r] = 0.f; }
  {
    u32* z1 = (u32*)&Shi[0][0];
    u32* z2 = (u32*)&Slo[0][0];
    for (int i = t; i < 2112; i += 256) { z1[i] = 0; z2[i] = 0; }
  }
  __syncthreads();
  const ushort_t* ap = (isU ? wp : qp) + (size_t)(Mt * 16 + l16) * 256;
  const ushort_t* kr = kp + (size_t)l16 * 32 + lquad * 8;
  const float* urow = up + (size_t)(Mt * 16 + lquad * 4) * 256 + j0 + l16;

  short8 aC[8], kC[4];
  floatx4 uC = {0.f, 0.f, 0.f, 0.f};
#pragma unroll
  for (int ks = 0; ks < 8; ++ks)
    aC[ks] = *(const short8*)(ap + ks * 32 + lquad * 8);
#pragma unroll
  for (int i = 0; i < 4; ++i)
    kC[i] = *(const short8*)(kr + (size_t)(wv * 4 + i) * 512);
  if (isU) {
#pragma unroll
    for (int r = 0; r < 4; ++r) uC[r] = urow[(size_t)r * 256];
  }

  for (int cc = 0; cc < NCh; ++cc) {
    size_t cb = (size_t)cc * 8192;
    short8 aN[8], kN[4];
    floatx4 uN = {0.f, 0.f, 0.f, 0.f};
    bool hasN = (cc + 1 < NCh);
    if (hasN) {
      size_t nb = cb + 8192;
#pragma unroll
      for (int ks = 0; ks < 8; ++ks)
        aN[ks] = *(const short8*)(ap + nb + ks * 32 + lquad * 8);
#pragma unroll
      for (int i = 0; i < 4; ++i)
        kN[i] = *(const short8*)(kr + nb + (size_t)(wv * 4 + i) * 512);
      if (isU) {
#pragma unroll
        for (int r = 0; r < 4; ++r) uN[r] = urow[nb + (size_t)r * 256];
      }
    }
    // attn A-fragment for this chunk (o1 waves only), f32 -> hi/lo
    short8 ath, atl;
    if (!isU) {
      const float* ar = atp + (size_t)cc * 1024 + (size_t)(Mt * 16 + l16) * 32 + lquad * 8;
      cvt8(*(const float4*)ar, *(const float4*)(ar + 4), ath, atl);
    }
    floatx4 acc;
    if (isU) {
      floatx4 a0 = uC, a1 = {0,0,0,0}, a2 = {0,0,0,0}, a3 = {0,0,0,0};
#pragma unroll
      for (int ks = 0; ks < 8; ++ks) {
        short8 sh = *(const short8*)&Shi[l16][ks * 32 + lquad * 8];
        short8 sl = *(const short8*)&Slo[l16][ks * 32 + lquad * 8];
        if (ks & 1) {
          a1 = __builtin_amdgcn_mfma_f32_16x16x32_bf16(aC[ks], sh, a1, 0, 0, 0);
          a3 = __builtin_amdgcn_mfma_f32_16x16x32_bf16(aC[ks], sl, a3, 0, 0, 0);
        } else {
          a0 = __builtin_amdgcn_mfma_f32_16x16x32_bf16(aC[ks], sh, a0, 0, 0, 0);
          a2 = __builtin_amdgcn_mfma_f32_16x16x32_bf16(aC[ks], sl, a2, 0, 0, 0);
        }
      }
#pragma unroll
      for (int r = 0; r < 4; ++r) acc[r] = (a0[r] + a1[r]) + (a2[r] + a3[r]);
#pragma unroll
      for (int r = 0; r < 4; ++r)
        u2L[Mt * 16 + lquad * 4 + r][l16] = acc[r];
    } else {
      // o1 = q @ S : hi-part of S only (error ~|S_lo||q|, within budget)
      floatx4 a0 = {0,0,0,0}, a1 = {0,0,0,0};
#pragma unroll
      for (int ks = 0; ks < 8; ++ks) {
        short8 sh = *(const short8*)&Shi[l16][ks * 32 + lquad * 8];
        if (ks & 1) a1 = __builtin_amdgcn_mfma_f32_16x16x32_bf16(aC[ks], sh, a1, 0, 0, 0);
        else        a0 = __builtin_amdgcn_mfma_f32_16x16x32_bf16(aC[ks], sh, a0, 0, 0, 0);
      }
#pragma unroll
      for (int r = 0; r < 4; ++r) acc[r] = a0[r] + a1[r];
    }
    __syncthreads();   // u2L ready; Shi/Slo reads complete
    short8 uh, ul;
#pragma unroll
    for (int j = 0; j < 8; ++j) {
      float f = u2L[lquad * 8 + j][l16];
      ushort_t hi = f2bf(f);
      uh[j] = (short)hi;
      ul[j] = (short)f2bf(f - bf2f(hi));
    }
    if (!isU) {
      // delta = o1 + attn @ u2 (fused; u2 never leaves the chip)
      acc = __builtin_amdgcn_mfma_f32_16x16x32_bf16(ath, uh, acc, 0, 0, 0);
      acc = __builtin_amdgcn_mfma_f32_16x16x32_bf16(ath, ul, acc, 0, 0, 0);
      acc = __builtin_amdgcn_mfma_f32_16x16x32_bf16(atl, uh, acc, 0, 0, 0);
#pragma unroll
      for (int r = 0; r < 4; ++r) {
        int l = cc * 32 + Mt * 16 + lquad * 4 + r;
        delta_g[(((size_t)b * Ls + l) * NH + h) * 256 + j0 + l16] = acc[r];
      }
    }
#pragma unroll
    for (int i = 0; i < 4; ++i) {
      Sacc[i]  = __builtin_amdgcn_mfma_f32_16x16x32_bf16(kC[i], uh, Sacc[i], 0, 0, 0);
      SaccL[i] = __builtin_amdgcn_mfma_f32_16x16x32_bf16(kC[i], ul, SaccL[i], 0, 0, 0);
    }
#pragma unroll
    for (int i = 0; i < 4; ++i) {
      int dk0 = (wv * 4 + i) * 16 + lquad * 4;
      ushort4 h4, l4;
      ushort_t* hp = (ushort_t*)&h4;
      ushort_t* lp = (ushort_t*)&l4;
#pragma unroll
      for (int r = 0; r < 4; ++r) {
        float sv = Sacc[i][r] + SaccL[i][r];
        ushort_t hi = f2bf(sv);
        hp[r] = hi;
        lp[r] = f2bf(sv - bf2f(hi));
      }
      *(ushort4*)&Shi[l16][dk0] = h4;
      *(ushort4*)&Slo[l16][dk0] = l4;
    }
    __syncthreads();
    if (hasN) {
#pragma unroll
      for (int ks = 0; ks < 8; ++ks) aC[ks] = aN[ks];
#pragma unroll
      for (int i = 0; i < 4; ++i) kC[i] = kN[i];
      uC = uN;
    }
  }
}

// ------- FIR 63-tap + 3-tap causal depthwise over v ------------------------
__global__ __launch_bounds__(256) void fir_conv(
    const float* __restrict__ v, const float* __restrict__ wlg,
    const float* __restrict__ wsg, float* __restrict__ firl,
    float* __restrict__ firs)
{
  __shared__ float vt[256][71];
  int t = threadIdx.x;
  int lt = blockIdx.x & 255;
  int bh = blockIdx.x >> 8;
  int b = bh >> 2, h = bh & 3;
  int l0 = lt * 8;
  const float* vp = v + (size_t)bh * Ls * 256;
  for (int r = 0; r < 70; ++r) {
    int ls = l0 - 62 + r;
    vt[t][r] = (ls >= 0) ? vp[(size_t)ls * 256 + t] : 0.f;
  }
  float TL[63], TS3[3];
#pragma unroll
  for (int j = 0; j < 63; ++j) TL[j] = wlg[((size_t)h * 256 + t) * 63 + j];
#pragma unroll
  for (int j = 0; j < 3; ++j) TS3[j] = wsg[((size_t)h * 256 + t) * 3 + j];
  __syncthreads();
  float aL[8] = {0,0,0,0,0,0,0,0}, aS[8] = {0,0,0,0,0,0,0,0};
#pragma unroll
  for (int r = 0; r < 70; ++r) {
    float vm = vt[t][r];
#pragma unroll
    for (int p = 0; p < 8; ++p) {
      int jl = r - p;
      if (jl >= 0 && jl < 63) aL[p] = fmaf(vm, TL[jl], aL[p]);
      int jssrc = r - 60 - p;
      if (jssrc >= 0 && jssrc < 3) aS[p] = fmaf(vm, TS3[jssrc], aS[p]);
    }
  }
#pragma unroll
  for (int p = 0; p < 8; ++p) {
    int l = l0 + p;
    size_t ob = (((size_t)b * Ls + l) * NH + h) * 256 + t;
    firl[ob] = aL[p];
    firs[ob] = aS[p];
  }
}

// ------- gate_in (bf16) ----------------------------------------------------
__global__ __launch_bounds__(256) void build_gate_in_bf(
    const float* __restrict__ x, const float* __restrict__ firs,
    const float* __restrict__ firl, const float* __restrict__ delta,
    const float* __restrict__ v, ushort_t* __restrict__ gin)
{
  int mtok = blockIdx.x, t = threadIdx.x;
  int b = mtok >> 11, l = mtok & 2047;
  float4 xv = *(const float4*)(x + (size_t)mtok * 1024 + t * 4);
  ushort4 xo = make_ushort4(f2bf(xv.x), f2bf(xv.y), f2bf(xv.z), f2bf(xv.w));
  *(ushort4*)(gin + (size_t)mtok * 1056 + t * 4) = xo;
  int w = t >> 6, lane = t & 63;
  for (int br = 0; br < 4; ++br) {
    float s = 0.f, s2 = 0.f;
#pragma unroll
    for (int r = 0; r < 4; ++r) {
      int d = lane + r * 64;
      float val;
      if (br == 0)      val = firs [(size_t)mtok * 1024 + w * 256 + d];
      else if (br == 1) val = firl [(size_t)mtok * 1024 + w * 256 + d];
      else if (br == 2) val = delta[(size_t)mtok * 1024 + w * 256 + d];
      else              val = v[(((size_t)(b * NH + w)) * Ls + l) * 256 + d];
      s += val; s2 = fmaf(val, val, s2);
    }
#pragma unroll
    for (int off = 32; off; off >>= 1) {
      s += __shfl_down(s, off);
      s2 += __shfl_down(s2, off);
    }
    if (lane == 0) {
      float mean = s * (1.f / 256.f);
      float var = s2 * (1.f / 256.f) - mean * mean;
      gin[(size_t)mtok * 1056 + 1024 + br * 8 + w] = f2bf(mean);
      gin[(size_t)mtok * 1056 + 1024 + br * 8 + 4 + w] = f2bf(sqrtf(fmaxf(var, 1e-6f)));
    }
  }
}

// ------- logits -> gates (bf16 hidden input) -------------------------------
__global__ __launch_bounds__(256) void mlp2_gates(
    const ushort_t* __restrict__ mh, const float* __restrict__ W2,
    const float* __restrict__ b2, const float* __restrict__ glt,
    float* __restrict__ gates)
{
  int mtok = blockIdx.x, t = threadIdx.x;
  float p[16];
#pragma unroll
  for (int j = 0; j < 16; ++j) p[j] = 0.f;
  for (int k = t; k < 2048; k += 256) {
    float hv = bf2f(mh[(size_t)mtok * 2048 + k]);
    const float* wr = W2 + (size_t)k * 16;
#pragma unroll
    for (int j4 = 0; j4 < 4; ++j4) {
      float4 w4 = *(const float4*)(wr + j4 * 4);
      p[j4*4+0] = fmaf(hv, w4.x, p[j4*4+0]);
      p[j4*4+1] = fmaf(hv, w4.y, p[j4*4+1]);
      p[j4*4+2] = fmaf(hv, w4.z, p[j4*4+2]);
      p[j4*4+3] = fmaf(hv, w4.w, p[j4*4+3]);
    }
  }
#pragma unroll
  for (int j = 0; j < 16; ++j)
#pragma unroll
    for (int off = 32; off; off >>= 1) p[j] += __shfl_down(p[j], off);
  __shared__ float red[4][16];
  __shared__ float zl[16];
  int w = t >> 6;
  if ((t & 63) == 0) {
#pragma unroll
    for (int j = 0; j < 16; ++j) red[w][j] = p[j];
  }
  __syncthreads();
  if (t < 16) {
    float tot = red[0][t] + red[1][t] + red[2][t] + red[3][t] + b2[t];
    float tempv = log1pf(expf(glt[t >> 2])) + 1e-4f;
    zl[t] = tot / tempv;
  }
  __syncthreads();
  if (t < 4) {
    float z0 = zl[t*4], z1 = zl[t*4+1], z2 = zl[t*4+2], z3 = zl[t*4+3];
    float mx = fmaxf(fmaxf(z0, z1), fmaxf(z2, z3));
    float e0 = expf(z0 - mx), e1 = expf(z1 - mx), e2 = expf(z2 - mx), e3 = expf(z3 - mx);
    float inv = 1.f / (e0 + e1 + e2 + e3);
    gates[(size_t)mtok * 16 + t * 4 + 0] = e0 * inv;
    gates[(size_t)mtok * 16 + t * 4 + 1] = e1 * inv;
    gates[(size_t)mtok * 16 + t * 4 + 2] = e2 * inv;
    gates[(size_t)mtok * 16 + t * 4 + 3] = e3 * inv;
  }
}

// ------- o = gated mix, RMSNorm -> bf16 ------------------------------------
__global__ __launch_bounds__(256) void combine_norm_bf(
    const float* __restrict__ firs, const float* __restrict__ firl,
    const float* __restrict__ delta, const float* __restrict__ v,
    const float* __restrict__ gates, const float* __restrict__ onw,
    ushort_t* __restrict__ o)
{
  int mh = blockIdx.x;
  int mtok = mh >> 2, h = mh & 3;
  int t = threadIdx.x;
  int b = mtok >> 11, l = mtok & 2047;
  const float* g = gates + (size_t)mtok * 16 + h * 4;
  float w0 = g[0], w1 = g[1], w2 = g[2], w3 = g[3];
  size_t tb = (size_t)mtok * 1024 + h * 256 + t;
  float val = w0 * firs[tb] + w1 * firl[tb] + w2 * delta[tb]
            + w3 * v[(((size_t)(b * NH + h)) * Ls + l) * 256 + t];
  float s2 = val * val;
#pragma unroll
  for (int off = 32; off; off >>= 1) s2 += __shfl_down(s2, off);
  __shared__ float r4[4];
  if ((t & 63) == 0) r4[t >> 6] = s2;
  __syncthreads();
  float tot = r4[0] + r4[1] + r4[2] + r4[3];
  float rms = rsqrtf(tot * (1.f / 256.f) + 1e-5f);
  o[tb] = f2bf(val * rms * onw[t]);
}

// ---------------------------------------------------------------------------
extern "C" void kernel_launch(void* const* d_in, const int* in_sizes, int n_in,
                              void* d_out, int out_size, void* d_ws, size_t ws_size,
                              hipStream_t stream) {
  const float* x     = (const float*)d_in[0];
  const float* Wq    = (const float*)d_in[1];
  const float* Wk    = (const float*)d_in[2];
  const float* Wv    = (const float*)d_in[3];
  const float* Wb    = (const float*)d_in[4];
  const float* convq = (const float*)d_in[5];
  const float* convk = (const float*)d_in[6];
  const float* convv = (const float*)d_in[7];
  const float* firsw = (const float*)d_in[8];
  const float* firlw = (const float*)d_in[9];
  const float* mlpw1 = (const float*)d_in[10];
  const float* mlpb1 = (const float*)d_in[11];
  const float* mlpw2 = (const float*)d_in[12];
  const float* mlpb2 = (const float*)d_in[13];
  const float* glt   = (const float*)d_in[14];
  const float* onw   = (const float*)d_in[15];
  const float* Wo    = (const float*)d_in[16];
  float* ws = (float*)d_ws;

  ushort_t* x_bf   = (ushort_t*)(ws + off_firs);
  ushort_t* Wq_t   = (ushort_t*)(ws + off_firl);
  ushort_t* Wk_t   = (ushort_t*)(ws + off_firl + 524288);
  ushort_t* Wv_t   = (ushort_t*)(ws + off_firl + 1048576);
  ushort_t* gin_bf = (ushort_t*)(ws + off_gin);
  ushort_t* w1_t   = (ushort_t*)(ws + off_xk);
  ushort_t* o_bf   = (ushort_t*)(ws + off_xv);
  ushort_t* Wo_t   = (ushort_t*)(ws + off_beta);   // spans into attn (dead)
  ushort_t* mlph_bf= (ushort_t*)(ws + off_mlph);
  ushort_t* wn_bf  = (ushort_t*)(ws + off_firs);
  ushort_t* q_bf   = (ushort_t*)(ws + off_firs + 2097152);
  ushort_t* knT_bf = (ushort_t*)(ws + off_firl);
  float* kb_f = ws + off_gin;    // conv_prep kb (dead before gin_bf built)
  float* vb_f = ws + off_mlph;   // conv_prep vb (dead before mlph built)

  dim3 blk(256);
  // projections (bf16 MFMA) + beta
  to_bf16<<<2048, blk, 0, stream>>>(x, x_bf, 4194304);
  convT<<<dim3(32, 32), blk, 0, stream>>>(Wq, Wq_t, 1024, 1024);
  convT<<<dim3(32, 32), blk, 0, stream>>>(Wk, Wk_t, 1024, 1024);
  convT<<<dim3(32, 32), blk, 0, stream>>>(Wv, Wv_t, 1024, 1024);
  gemm_bf16<<<dim3(8, 32), blk, 0, stream>>>(x_bf, Wq_t, ws + off_xq, 1024, 1024, nullptr, 0, 0);
  gemm_bf16<<<dim3(8, 32), blk, 0, stream>>>(x_bf, Wk_t, ws + off_xk, 1024, 1024, nullptr, 0, 0);
  gemm_bf16<<<dim3(8, 32), blk, 0, stream>>>(x_bf, Wv_t, ws + off_xv, 1024, 1024, nullptr, 0, 0);
  beta_sigmoid<<<4096, blk, 0, stream>>>(x, Wb, ws + off_beta);
  // fused conv4+silu + l2norm + beta products
  conv_prep<<<16384, blk, 0, stream>>>(ws + off_xq, ws + off_xk, ws + off_xv,
                                       convq, convk, convv, ws + off_beta,
                                       ws + off_q, ws + off_k, kb_f, vb_f, ws + off_v);
  // per-chunk T inverse, attn, u (->xv), bf16 {-w, q, knT}
  chunk_prep<<<512, blk, 0, stream>>>(kb_f, ws + off_k, ws + off_q, vb_f,
                                      ws + off_attn, ws + off_xv, wn_bf, q_bf, knT_bf);
  // serial MFMA scan with fused attn@u2: delta -> off_q
  delta_chain_mfma<<<128, blk, 0, stream>>>(wn_bf, q_bf, knT_bf, ws + off_attn,
                                            ws + off_xv, ws + off_q);
  // FIR branches (overwrites wn_bf/q_bf/knT_bf regions — dead by now)
  fir_conv<<<2048, blk, 0, stream>>>(ws + off_v, firlw, firsw, ws + off_firl, ws + off_firs);
  // gate input (bf16), MLP1 (MFMA, gelu, bf16 out), gates
  build_gate_in_bf<<<4096, blk, 0, stream>>>(x, ws + off_firs, ws + off_firl, ws + off_q,
                                             ws + off_v, gin_bf);
  convT<<<dim3(64, 33), blk, 0, stream>>>(mlpw1, w1_t, 1056, 2048);
  gemm_bf16<<<dim3(16, 32), blk, 0, stream>>>(gin_bf, w1_t, (float*)mlph_bf,
                                              2048, 1056, mlpb1, 1, 1);
  mlp2_gates<<<4096, blk, 0, stream>>>(mlph_bf, mlpw2, mlpb2, glt, ws + off_gates);
  // combine + RMSNorm -> bf16, output projection (MFMA)
  combine_norm_bf<<<16384, blk, 0, stream>>>(ws + off_firs, ws + off_firl, ws + off_q,
                                             ws + off_v, ws + off_gates, onw, o_bf);
  convT<<<dim3(32, 32), blk, 0, stream>>>(Wo, Wo_t, 1024, 1024);
  gemm_bf16<<<dim3(8, 32), blk, 0, stream>>>(o_bf, Wo_t, (float*)d_out, 1024, 1024, nullptr, 0, 0);
}

// Round 7
// 580.048 us; speedup vs baseline: 1.2217x; 1.2217x over previous
//
#include <hip/hip_runtime.h>
#include <hip/hip_bf16.h>

// ---------------------------------------------------------------------------
// DeltaNet forward, round 7:
//  - delta_chain: attn fragment double-buffered (round-6 bug: same-iteration
//    attn load forced vmcnt(0) drain of all prefetches -> +46us).
//  - fir_conv co-scheduled INSIDE the chain launch (grid 128 chain blocks +
//    2048 fir blocks, unioned LDS) -> fir rides the chain's idle CUs.
//    fir outputs relocated to dead x3 regions (off_xq / off_xk).
//  - q/k/v projections fused into ONE gemm (N=3072, weights already
//    contiguous); conv_prep reads the [m][3072] fused layout.
// ---------------------------------------------------------------------------

#define DEVI __device__ __forceinline__
typedef unsigned int u32;
typedef unsigned short ushort_t;
typedef __attribute__((ext_vector_type(8))) short short8;
typedef __attribute__((ext_vector_type(4))) float floatx4;

constexpr int Ls = 2048, NH = 4;
constexpr int NCh = 64;

// workspace offsets (floats)
constexpr size_t off_xq   = 0;         // x3 [m][3072] cols 0-1023 -> firs
constexpr size_t off_xk   = 4194304;   // x3 cols 1024-2047 -> firl
constexpr size_t off_xv   = 8388608;   // x3 cols 2048-3071 -> u -> o_bf
constexpr size_t off_q    = 12582912;  // qn -> delta
constexpr size_t off_k    = 16777216;  // kn -> w1_t (bf16)
constexpr size_t off_v    = 20971520;  // v (alive to the end)
constexpr size_t off_beta = 25165824;  // beta -> Wo_t (bf16, spans into attn)
constexpr size_t off_attn = 25182208;  // attn (dead after chain)
constexpr size_t off_firs = 25706496;  // x_bf -> {wn_bf, q_bf} (bf16)
constexpr size_t off_firl = 29900800;  // Wqkv_t -> knT_bf (bf16)
constexpr size_t off_gin  = 34095104;  // kb (f32) -> gin_bf
constexpr size_t off_mlph = 38420480;  // vb (f32) -> mlph_bf
constexpr size_t off_gates= 46809088;  // gates

DEVI float sigmoidf_(float x) { return 1.f / (1.f + expf(-x)); }
DEVI float siluf_(float x) { return x / (1.f + expf(-x)); }
DEVI float geluf_(float x) { return 0.5f * x * (1.f + erff(x * 0.7071067811865476f)); }
DEVI ushort_t f2bf(float f) {
  union { float f; u32 u; } c{f};
  u32 r = (c.u + 0x7fffu + ((c.u >> 16) & 1u)) >> 16;
  return (ushort_t)r;
}
DEVI float bf2f(ushort_t h) {
  union { u32 u; float f; } c; c.u = ((u32)h) << 16; return c.f;
}
DEVI void cvt8(float4 a, float4 b, short8& hi, short8& lo) {
  float f[8] = {a.x,a.y,a.z,a.w,b.x,b.y,b.z,b.w};
#pragma unroll
  for (int j = 0; j < 8; ++j) {
    ushort_t h = f2bf(f[j]);
    hi[j] = (short)h;
    lo[j] = (short)f2bf(f[j] - bf2f(h));
  }
}
DEVI void async16(const void* g, void* l) {
  __builtin_amdgcn_global_load_lds(
      (const u32 __attribute__((address_space(1)))*)g,
      (u32 __attribute__((address_space(3)))*)l, 16, 0, 0);
}

// ---------------- f32 -> bf16 ----------------------------------------------
__global__ __launch_bounds__(256) void to_bf16(
    const float* __restrict__ in, ushort_t* __restrict__ out, int n)
{
  int i = (blockIdx.x * 256 + threadIdx.x) * 8;
  if (i >= n) return;
  float4 a = *(const float4*)(in + i);
  float4 b = *(const float4*)(in + i + 4);
  ushort_t o[8] = { f2bf(a.x), f2bf(a.y), f2bf(a.z), f2bf(a.w),
                    f2bf(b.x), f2bf(b.y), f2bf(b.z), f2bf(b.w) };
  *(uint4*)(out + i) = *(uint4*)o;
}

// ---------------- f32 [K][N] -> bf16 [N][K] --------------------------------
__global__ __launch_bounds__(256) void convT(
    const float* __restrict__ W, ushort_t* __restrict__ out, int Kq, int Nq)
{
  __shared__ ushort_t tile[32][33];
  int n0 = blockIdx.x * 32, k0 = blockIdx.y * 32;
  int tx = threadIdx.x & 31, ty = threadIdx.x >> 5;
#pragma unroll
  for (int r = 0; r < 32; r += 8)
    tile[ty + r][tx] = f2bf(W[(size_t)(k0 + ty + r) * Nq + n0 + tx]);
  __syncthreads();
#pragma unroll
  for (int r = 0; r < 32; r += 8)
    out[(size_t)(n0 + ty + r) * Kq + k0 + tx] = tile[tx][ty + r];
}

// ---------------- bf16 MFMA GEMM -------------------------------------------
__global__ __launch_bounds__(256) void gemm_bf16(
    const ushort_t* __restrict__ A, const ushort_t* __restrict__ Bt,
    float* __restrict__ C, int Nq, int Kq,
    const float* __restrict__ bias, int act, int outbf)
{
  __shared__ ushort_t As[128 * 32];
  __shared__ ushort_t Bs[128 * 32];
  int t = threadIdx.x;
  int w = t >> 6, lane = t & 63;
  int m0 = blockIdx.y * 128, n0 = blockIdx.x * 128;
  floatx4 acc[4][4];
#pragma unroll
  for (int i = 0; i < 4; ++i)
#pragma unroll
    for (int j = 0; j < 4; ++j)
#pragma unroll
      for (int r = 0; r < 4; ++r) acc[i][j][r] = 0.f;

  int lrow = lane >> 2, lk8 = (lane & 3) * 8;
  for (int kt = 0; kt < Kq; kt += 32) {
#pragma unroll
    for (int r = 0; r < 2; ++r) {
      int seg = w * 2 + r;
      int row = seg * 16 + lrow;
      async16(A  + (size_t)(m0 + row) * Kq + kt + lk8, &As[seg * 512]);
      async16(Bt + (size_t)(n0 + row) * Kq + kt + lk8, &Bs[seg * 512]);
    }
    __syncthreads();
    short8 af[4], bf[4];
#pragma unroll
    for (int i = 0; i < 4; ++i) {
      int row = (w >> 1) * 64 + i * 16 + (lane & 15);
      af[i] = *(const short8*)&As[row * 32 + (lane >> 4) * 8];
    }
#pragma unroll
    for (int j = 0; j < 4; ++j) {
      int col = (w & 1) * 64 + j * 16 + (lane & 15);
      bf[j] = *(const short8*)&Bs[col * 32 + (lane >> 4) * 8];
    }
#pragma unroll
    for (int i = 0; i < 4; ++i)
#pragma unroll
      for (int j = 0; j < 4; ++j)
        acc[i][j] = __builtin_amdgcn_mfma_f32_16x16x32_bf16(af[i], bf[j], acc[i][j], 0, 0, 0);
    __syncthreads();
  }
#pragma unroll
  for (int i = 0; i < 4; ++i) {
    int rbase = m0 + (w >> 1) * 64 + i * 16 + ((lane >> 4) << 2);
#pragma unroll
    for (int j = 0; j < 4; ++j) {
      int col = n0 + (w & 1) * 64 + j * 16 + (lane & 15);
      float bv = act ? bias[col] : 0.f;
#pragma unroll
      for (int r = 0; r < 4; ++r) {
        float v = acc[i][j][r];
        if (act) v = geluf_(v + bv);
        if (outbf) ((ushort_t*)C)[(size_t)(rbase + r) * Nq + col] = f2bf(v);
        else       C[(size_t)(rbase + r) * Nq + col] = v;
      }
    }
  }
}

// ---------------- beta = sigmoid(x @ Wb) -----------------------------------
__global__ __launch_bounds__(256) void beta_sigmoid(
    const float* __restrict__ x, const float* __restrict__ Wb,
    float* __restrict__ beta)
{
  int mtok = blockIdx.x, t = threadIdx.x;
  int b = mtok >> 11, l = mtok & 2047;
  float a0 = 0, a1 = 0, a2 = 0, a3 = 0;
  for (int k = t; k < 1024; k += 256) {
    float xv = x[(size_t)mtok * 1024 + k];
    float4 w4 = *(const float4*)(Wb + k * 4);
    a0 = fmaf(xv, w4.x, a0); a1 = fmaf(xv, w4.y, a1);
    a2 = fmaf(xv, w4.z, a2); a3 = fmaf(xv, w4.w, a3);
  }
#pragma unroll
  for (int off = 32; off; off >>= 1) {
    a0 += __shfl_down(a0, off); a1 += __shfl_down(a1, off);
    a2 += __shfl_down(a2, off); a3 += __shfl_down(a3, off);
  }
  __shared__ float red[4][4];
  int w = t >> 6;
  if ((t & 63) == 0) { red[w][0] = a0; red[w][1] = a1; red[w][2] = a2; red[w][3] = a3; }
  __syncthreads();
  if (t < 4) {
    float s = red[0][t] + red[1][t] + red[2][t] + red[3][t];
    beta[((size_t)(b * NH + t)) * Ls + l] = sigmoidf_(s);
  }
}

// ------- fused conv4+silu (from fused x3 [m][3072]) + l2norm + beta --------
__global__ __launch_bounds__(256) void conv_prep(
    const float* __restrict__ x3, const float* __restrict__ wq,
    const float* __restrict__ wk, const float* __restrict__ wv,
    const float* __restrict__ beta_g,
    float* __restrict__ qn, float* __restrict__ kn,
    float* __restrict__ kb, float* __restrict__ vb,
    float* __restrict__ v_out)
{
  int i = blockIdx.x;              // bh*Ls + l
  int t = threadIdx.x;
  int l = i & 2047, bh = i >> 11;
  int b = bh >> 2, h = bh & 3;
  int c = h * 256 + t;
  const float* p = x3 + ((size_t)b * Ls) * 3072 + c;
  float4 wq4 = *(const float4*)(wq + c * 4);
  float4 wk4 = *(const float4*)(wk + c * 4);
  float4 wv4 = *(const float4*)(wv + c * 4);
  float qw[4] = {wq4.x, wq4.y, wq4.z, wq4.w};
  float kw[4] = {wk4.x, wk4.y, wk4.z, wk4.w};
  float vw[4] = {wv4.x, wv4.y, wv4.z, wv4.w};
  float aq = 0.f, ak = 0.f, av = 0.f;
#pragma unroll
  for (int j = 0; j < 4; ++j) {
    int ls = l - 3 + j;
    if (ls >= 0) {
      size_t rb = (size_t)ls * 3072;
      aq = fmaf(qw[j], p[rb], aq);
      ak = fmaf(kw[j], p[rb + 1024], ak);
      av = fmaf(vw[j], p[rb + 2048], av);
    }
  }
  float qv = siluf_(aq), kv = siluf_(ak), vv = siluf_(av);
  float sq = qv * qv, sk = kv * kv;
#pragma unroll
  for (int off = 32; off; off >>= 1) {
    sq += __shfl_down(sq, off);
    sk += __shfl_down(sk, off);
  }
  __shared__ float rq_[4], rk_[4];
  int w = t >> 6;
  if ((t & 63) == 0) { rq_[w] = sq; rk_[w] = sk; }
  __syncthreads();
  sq = rq_[0] + rq_[1] + rq_[2] + rq_[3];
  sk = rk_[0] + rk_[1] + rk_[2] + rk_[3];
  float rq = rsqrtf(sq + 1e-6f), rk = rsqrtf(sk + 1e-6f);
  float bt = beta_g[i];
  size_t base = (size_t)i * 256 + t;
  qn[base] = qv * rq;
  kn[base] = kv * rk;
  kb[base] = kv * rk * bt;
  vb[base] = vv * bt;
  v_out[base] = vv;
}

// ------- per (b,h,chunk) MFMA: Gram, substitution, w/u applies -------------
__global__ __launch_bounds__(256) void chunk_prep(
    const float* __restrict__ kb, const float* __restrict__ kn,
    const float* __restrict__ qn, const float* __restrict__ vb,
    float* __restrict__ attn_g, float* __restrict__ u_out,
    ushort_t* __restrict__ wn_bf, ushort_t* __restrict__ q_bf,
    ushort_t* __restrict__ knT_bf)
{
  __shared__ float Am[32][33];
  __shared__ float Tm[32][36];
  __shared__ ushort_t KT_hi[256][40];
  __shared__ ushort_t KT_lo[256][40];
  int t = threadIdx.x;
  int cc = blockIdx.x & 63, bh = blockIdx.x >> 6;
  size_t gbase = ((size_t)bh * Ls + cc * 32) * 256;
  int wv = t >> 6, lane = t & 63;
  int l16 = lane & 15, quad = lane >> 4;
  int mi = wv >> 1, ni = wv & 1;

  floatx4 Aacc = {0.f,0.f,0.f,0.f}, Qacc = {0.f,0.f,0.f,0.f};
  {
    int mrow = mi * 16 + l16, nrow = ni * 16 + l16;
    const float* kbp = kb + gbase + (size_t)mrow * 256;
    const float* qnp = qn + gbase + (size_t)mrow * 256;
    const float* knp = kn + gbase + (size_t)nrow * 256;
#pragma unroll
    for (int ks = 0; ks < 8; ++ks) {
      int koff = ks * 32 + quad * 8;
      short8 kbh, kbl, qnh, qnl, knh, knl;
      cvt8(*(const float4*)(kbp + koff), *(const float4*)(kbp + koff + 4), kbh, kbl);
      cvt8(*(const float4*)(qnp + koff), *(const float4*)(qnp + koff + 4), qnh, qnl);
      cvt8(*(const float4*)(knp + koff), *(const float4*)(knp + koff + 4), knh, knl);
      Aacc = __builtin_amdgcn_mfma_f32_16x16x32_bf16(kbh, knh, Aacc, 0, 0, 0);
      Aacc = __builtin_amdgcn_mfma_f32_16x16x32_bf16(kbh, knl, Aacc, 0, 0, 0);
      Aacc = __builtin_amdgcn_mfma_f32_16x16x32_bf16(kbl, knh, Aacc, 0, 0, 0);
      Qacc = __builtin_amdgcn_mfma_f32_16x16x32_bf16(qnh, knh, Qacc, 0, 0, 0);
      Qacc = __builtin_amdgcn_mfma_f32_16x16x32_bf16(qnh, knl, Qacc, 0, 0, 0);
      Qacc = __builtin_amdgcn_mfma_f32_16x16x32_bf16(qnl, knh, Qacc, 0, 0, 0);
      if (ni == 0)
        *(uint4*)(q_bf + gbase + (size_t)mrow * 256 + koff) = *(uint4*)&qnh;
    }
  }
  float* ag = attn_g + ((size_t)bh * 64 + cc) * 1024;
#pragma unroll
  for (int r = 0; r < 4; ++r) {
    int row = mi * 16 + quad * 4 + r, col = ni * 16 + l16;
    Am[row][col] = (col < row) ? Aacc[r] : 0.f;
    ag[row * 32 + col] = (col <= row) ? Qacc[r] : 0.f;
  }
  __syncthreads();

  if (wv == 0) {
    if (t < 32) {
#pragma unroll
      for (int i = 0; i < 32; ++i) Tm[i][t] = (i == t) ? 1.f : 0.f;
      for (int i2 = 1; i2 < 32; ++i2) {
        if (t < i2) {
          float s = 0.f;
          for (int m2 = t; m2 < i2; ++m2) s = fmaf(Am[i2][m2], Tm[m2][t], s);
          Tm[i2][t] = -s;
        }
      }
    }
  } else {
    int base = t - 64;
#pragma unroll
    for (int pass = 0; pass < 2; ++pass) {
      int d = base + pass * 192;
      if (d < 256) {
        u32 hp[16], lp[16], kp2[16];
#pragma unroll
        for (int m2 = 0; m2 < 16; ++m2) {
          float f0 = kb[gbase + (size_t)(2 * m2) * 256 + d];
          float f1 = kb[gbase + (size_t)(2 * m2 + 1) * 256 + d];
          ushort_t h0 = f2bf(f0), h1 = f2bf(f1);
          hp[m2] = (u32)h0 | ((u32)h1 << 16);
          lp[m2] = (u32)f2bf(f0 - bf2f(h0)) | ((u32)f2bf(f1 - bf2f(h1)) << 16);
          float g0 = kn[gbase + (size_t)(2 * m2) * 256 + d];
          float g1 = kn[gbase + (size_t)(2 * m2 + 1) * 256 + d];
          kp2[m2] = (u32)f2bf(g0) | ((u32)f2bf(g1) << 16);
        }
#pragma unroll
        for (int q2 = 0; q2 < 4; ++q2) {
          *(uint4*)&KT_hi[d][q2 * 8] = *(uint4*)&hp[q2 * 4];
          *(uint4*)&KT_lo[d][q2 * 8] = *(uint4*)&lp[q2 * 4];
          *(uint4*)(knT_bf + gbase + (size_t)d * 32 + q2 * 8) = *(uint4*)&kp2[q2 * 4];
        }
      }
    }
  }
  __syncthreads();

  int lt = wv & 1, dgrp = wv >> 1;
  short8 Th, Tl;
  {
    int lrow = lt * 16 + l16;
    cvt8(*(const float4*)&Tm[lrow][quad * 8],
         *(const float4*)&Tm[lrow][quad * 8 + 4], Th, Tl);
  }
#pragma unroll
  for (int j = 0; j < 8; ++j) {
    int dt = dgrp * 8 + j;
    short8 Bh = *(const short8*)&KT_hi[dt * 16 + l16][quad * 8];
    short8 Bl = *(const short8*)&KT_lo[dt * 16 + l16][quad * 8];
    floatx4 acc = {0.f,0.f,0.f,0.f};
    acc = __builtin_amdgcn_mfma_f32_16x16x32_bf16(Th, Bh, acc, 0, 0, 0);
    acc = __builtin_amdgcn_mfma_f32_16x16x32_bf16(Th, Bl, acc, 0, 0, 0);
    acc = __builtin_amdgcn_mfma_f32_16x16x32_bf16(Tl, Bh, acc, 0, 0, 0);
#pragma unroll
    for (int r = 0; r < 4; ++r) {
      int row = lt * 16 + quad * 4 + r;
      wn_bf[gbase + (size_t)row * 256 + dt * 16 + l16] = f2bf(-acc[r]);
    }
  }
  __syncthreads();

  {
    int d = t;
    u32 hp[16], lp[16];
#pragma unroll
    for (int m2 = 0; m2 < 16; ++m2) {
      float f0 = vb[gbase + (size_t)(2 * m2) * 256 + d];
      float f1 = vb[gbase + (size_t)(2 * m2 + 1) * 256 + d];
      ushort_t h0 = f2bf(f0), h1 = f2bf(f1);
      hp[m2] = (u32)h0 | ((u32)h1 << 16);
      lp[m2] = (u32)f2bf(f0 - bf2f(h0)) | ((u32)f2bf(f1 - bf2f(h1)) << 16);
    }
#pragma unroll
    for (int q2 = 0; q2 < 4; ++q2) {
      *(uint4*)&KT_hi[d][q2 * 8] = *(uint4*)&hp[q2 * 4];
      *(uint4*)&KT_lo[d][q2 * 8] = *(uint4*)&lp[q2 * 4];
    }
  }
  __syncthreads();

#pragma unroll
  for (int j = 0; j < 8; ++j) {
    int dt = dgrp * 8 + j;
    short8 Bh = *(const short8*)&KT_hi[dt * 16 + l16][quad * 8];
    short8 Bl = *(const short8*)&KT_lo[dt * 16 + l16][quad * 8];
    floatx4 acc = {0.f,0.f,0.f,0.f};
    acc = __builtin_amdgcn_mfma_f32_16x16x32_bf16(Th, Bh, acc, 0, 0, 0);
    acc = __builtin_amdgcn_mfma_f32_16x16x32_bf16(Th, Bl, acc, 0, 0, 0);
    acc = __builtin_amdgcn_mfma_f32_16x16x32_bf16(Tl, Bh, acc, 0, 0, 0);
#pragma unroll
    for (int r = 0; r < 4; ++r) {
      int row = lt * 16 + quad * 4 + r;
      u_out[gbase + (size_t)row * 256 + dt * 16 + l16] = acc[r];
    }
  }
}

// ------- merged: MFMA serial scan (blocks 0-127) + FIR conv (blocks 128+) --
__global__ __launch_bounds__(256, 1) void delta_fir(
    const ushort_t* __restrict__ wn_bf, const ushort_t* __restrict__ q_bf,
    const ushort_t* __restrict__ knT_bf, const float* __restrict__ attn_g,
    const float* __restrict__ u_g, float* __restrict__ delta_g,
    const float* __restrict__ v, const float* __restrict__ wlg,
    const float* __restrict__ wsg, float* __restrict__ firl,
    float* __restrict__ firs)
{
  __shared__ __attribute__((aligned(16))) char smem[72704];
  int t = threadIdx.x;

  if (blockIdx.x >= 128) {
    // ---------------- FIR part ----------------
    float (*vt)[71] = (float(*)[71])smem;
    int bid = blockIdx.x - 128;
    int lt = bid & 255;
    int bh = bid >> 8;
    int b = bh >> 2, h = bh & 3;
    int l0 = lt * 8;
    const float* vp = v + (size_t)bh * Ls * 256;
    for (int r = 0; r < 70; ++r) {
      int ls = l0 - 62 + r;
      vt[t][r] = (ls >= 0) ? vp[(size_t)ls * 256 + t] : 0.f;
    }
    float TL[63], TS3[3];
#pragma unroll
    for (int j = 0; j < 63; ++j) TL[j] = wlg[((size_t)h * 256 + t) * 63 + j];
#pragma unroll
    for (int j = 0; j < 3; ++j) TS3[j] = wsg[((size_t)h * 256 + t) * 3 + j];
    __syncthreads();
    float aL[8] = {0,0,0,0,0,0,0,0}, aS[8] = {0,0,0,0,0,0,0,0};
#pragma unroll
    for (int r = 0; r < 70; ++r) {
      float vm = vt[t][r];
#pragma unroll
      for (int p = 0; p < 8; ++p) {
        int jl = r - p;
        if (jl >= 0 && jl < 63) aL[p] = fmaf(vm, TL[jl], aL[p]);
        int jssrc = r - 60 - p;
        if (jssrc >= 0 && jssrc < 3) aS[p] = fmaf(vm, TS3[jssrc], aS[p]);
      }
    }
#pragma unroll
    for (int p = 0; p < 8; ++p) {
      int l = l0 + p;
      size_t ob = (((size_t)b * Ls + l) * NH + h) * 256 + t;
      firl[ob] = aL[p];
      firs[ob] = aS[p];
    }
    return;
  }

  // ---------------- chain part ----------------
  ushort_t (*Shi)[264] = (ushort_t(*)[264])(smem);
  ushort_t (*Slo)[264] = (ushort_t(*)[264])(smem + 8448);
  float (*u2L)[17] = (float(*)[17])(smem + 16896);
  int bh = blockIdx.x & 7, g = blockIdx.x >> 3;
  int b = bh >> 2, h = bh & 3;
  int wv = t >> 6, lane = t & 63;
  int lquad = lane >> 4, l16 = lane & 15;
  int j0 = g * 16;
  const ushort_t* wp = wn_bf + (size_t)bh * Ls * 256;
  const ushort_t* qp = q_bf  + (size_t)bh * Ls * 256;
  const ushort_t* kp = knT_bf + (size_t)bh * Ls * 256;
  const float* up = u_g + (size_t)bh * Ls * 256;
  const float* atp = attn_g + (size_t)bh * 64 * 1024;
  int Mt = wv & 1;
  bool isU = (wv < 2);
  floatx4 Sacc[4], SaccL[4];
#pragma unroll
  for (int i = 0; i < 4; ++i)
#pragma unroll
    for (int r = 0; r < 4; ++r) { Sacc[i][r] = 0.f; SaccL[i][r] = 0.f; }
  for (int i = t; i < 4224; i += 256) ((u32*)smem)[i] = 0;
  __syncthreads();
  const ushort_t* ap = (isU ? wp : qp) + (size_t)(Mt * 16 + l16) * 256;
  const ushort_t* kr = kp + (size_t)l16 * 32 + lquad * 8;
  const float* urow = up + (size_t)(Mt * 16 + lquad * 4) * 256 + j0 + l16;
  const float* arp = atp + (size_t)(Mt * 16 + l16) * 32 + lquad * 8;

  // prologue: chunk-0 operands (incl. attn for o-waves)
  short8 aC[8], kC[4];
  floatx4 uC = {0.f, 0.f, 0.f, 0.f};
  float4 atC0 = {0,0,0,0}, atC1 = {0,0,0,0};
#pragma unroll
  for (int ks = 0; ks < 8; ++ks)
    aC[ks] = *(const short8*)(ap + ks * 32 + lquad * 8);
#pragma unroll
  for (int i = 0; i < 4; ++i)
    kC[i] = *(const short8*)(kr + (size_t)(wv * 4 + i) * 512);
  if (isU) {
#pragma unroll
    for (int r = 0; r < 4; ++r) uC[r] = urow[(size_t)r * 256];
  } else {
    atC0 = *(const float4*)(arp);
    atC1 = *(const float4*)(arp + 4);
  }

  for (int cc = 0; cc < NCh; ++cc) {
    size_t cb = (size_t)cc * 8192;
    // issue next-chunk loads (incl. attn) before any use of current regs
    short8 aN[8], kN[4];
    floatx4 uN = {0.f, 0.f, 0.f, 0.f};
    float4 atN0 = {0,0,0,0}, atN1 = {0,0,0,0};
    bool hasN = (cc + 1 < NCh);
    if (hasN) {
      size_t nb = cb + 8192;
#pragma unroll
      for (int ks = 0; ks < 8; ++ks)
        aN[ks] = *(const short8*)(ap + nb + ks * 32 + lquad * 8);
#pragma unroll
      for (int i = 0; i < 4; ++i)
        kN[i] = *(const short8*)(kr + nb + (size_t)(wv * 4 + i) * 512);
      if (isU) {
#pragma unroll
        for (int r = 0; r < 4; ++r) uN[r] = urow[nb + (size_t)r * 256];
      } else {
        size_t na = (size_t)(cc + 1) * 1024;
        atN0 = *(const float4*)(arp + na);
        atN1 = *(const float4*)(arp + na + 4);
      }
    }
    // attn fragment cvt from LAST-iteration registers (no memory wait)
    short8 ath, atl;
    if (!isU) cvt8(atC0, atC1, ath, atl);

    floatx4 acc;
    if (isU) {
      floatx4 a0 = uC, a1 = {0,0,0,0}, a2 = {0,0,0,0}, a3 = {0,0,0,0};
#pragma unroll
      for (int ks = 0; ks < 8; ++ks) {
        short8 sh = *(const short8*)&Shi[l16][ks * 32 + lquad * 8];
        short8 sl = *(const short8*)&Slo[l16][ks * 32 + lquad * 8];
        if (ks & 1) {
          a1 = __builtin_amdgcn_mfma_f32_16x16x32_bf16(aC[ks], sh, a1, 0, 0, 0);
          a3 = __builtin_amdgcn_mfma_f32_16x16x32_bf16(aC[ks], sl, a3, 0, 0, 0);
        } else {
          a0 = __builtin_amdgcn_mfma_f32_16x16x32_bf16(aC[ks], sh, a0, 0, 0, 0);
          a2 = __builtin_amdgcn_mfma_f32_16x16x32_bf16(aC[ks], sl, a2, 0, 0, 0);
        }
      }
#pragma unroll
      for (int r = 0; r < 4; ++r) acc[r] = (a0[r] + a1[r]) + (a2[r] + a3[r]);
#pragma unroll
      for (int r = 0; r < 4; ++r)
        u2L[Mt * 16 + lquad * 4 + r][l16] = acc[r];
    } else {
      floatx4 a0 = {0,0,0,0}, a1 = {0,0,0,0};
#pragma unroll
      for (int ks = 0; ks < 8; ++ks) {
        short8 sh = *(const short8*)&Shi[l16][ks * 32 + lquad * 8];
        if (ks & 1) a1 = __builtin_amdgcn_mfma_f32_16x16x32_bf16(aC[ks], sh, a1, 0, 0, 0);
        else        a0 = __builtin_amdgcn_mfma_f32_16x16x32_bf16(aC[ks], sh, a0, 0, 0, 0);
      }
#pragma unroll
      for (int r = 0; r < 4; ++r) acc[r] = a0[r] + a1[r];
    }
    __syncthreads();   // u2L ready; Shi/Slo reads complete
    short8 uh, ul;
#pragma unroll
    for (int j = 0; j < 8; ++j) {
      float f = u2L[lquad * 8 + j][l16];
      ushort_t hi = f2bf(f);
      uh[j] = (short)hi;
      ul[j] = (short)f2bf(f - bf2f(hi));
    }
    if (!isU) {
      acc = __builtin_amdgcn_mfma_f32_16x16x32_bf16(ath, uh, acc, 0, 0, 0);
      acc = __builtin_amdgcn_mfma_f32_16x16x32_bf16(ath, ul, acc, 0, 0, 0);
      acc = __builtin_amdgcn_mfma_f32_16x16x32_bf16(atl, uh, acc, 0, 0, 0);
#pragma unroll
      for (int r = 0; r < 4; ++r) {
        int l = cc * 32 + Mt * 16 + lquad * 4 + r;
        delta_g[(((size_t)b * Ls + l) * NH + h) * 256 + j0 + l16] = acc[r];
      }
    }
#pragma unroll
    for (int i = 0; i < 4; ++i) {
      Sacc[i]  = __builtin_amdgcn_mfma_f32_16x16x32_bf16(kC[i], uh, Sacc[i], 0, 0, 0);
      SaccL[i] = __builtin_amdgcn_mfma_f32_16x16x32_bf16(kC[i], ul, SaccL[i], 0, 0, 0);
    }
#pragma unroll
    for (int i = 0; i < 4; ++i) {
      int dk0 = (wv * 4 + i) * 16 + lquad * 4;
      ushort4 h4, l4;
      ushort_t* hp = (ushort_t*)&h4;
      ushort_t* lp = (ushort_t*)&l4;
#pragma unroll
      for (int r = 0; r < 4; ++r) {
        float sv = Sacc[i][r] + SaccL[i][r];
        ushort_t hi = f2bf(sv);
        hp[r] = hi;
        lp[r] = f2bf(sv - bf2f(hi));
      }
      *(ushort4*)&Shi[l16][dk0] = h4;
      *(ushort4*)&Slo[l16][dk0] = l4;
    }
    __syncthreads();
    if (hasN) {
#pragma unroll
      for (int ks = 0; ks < 8; ++ks) aC[ks] = aN[ks];
#pragma unroll
      for (int i = 0; i < 4; ++i) kC[i] = kN[i];
      uC = uN;
      atC0 = atN0; atC1 = atN1;
    }
  }
}

// ------- gate_in (bf16) ----------------------------------------------------
__global__ __launch_bounds__(256) void build_gate_in_bf(
    const float* __restrict__ x, const float* __restrict__ firs,
    const float* __restrict__ firl, const float* __restrict__ delta,
    const float* __restrict__ v, ushort_t* __restrict__ gin)
{
  int mtok = blockIdx.x, t = threadIdx.x;
  int b = mtok >> 11, l = mtok & 2047;
  float4 xv = *(const float4*)(x + (size_t)mtok * 1024 + t * 4);
  ushort4 xo = make_ushort4(f2bf(xv.x), f2bf(xv.y), f2bf(xv.z), f2bf(xv.w));
  *(ushort4*)(gin + (size_t)mtok * 1056 + t * 4) = xo;
  int w = t >> 6, lane = t & 63;
  for (int br = 0; br < 4; ++br) {
    float s = 0.f, s2 = 0.f;
#pragma unroll
    for (int r = 0; r < 4; ++r) {
      int d = lane + r * 64;
      float val;
      if (br == 0)      val = firs [(size_t)mtok * 1024 + w * 256 + d];
      else if (br == 1) val = firl [(size_t)mtok * 1024 + w * 256 + d];
      else if (br == 2) val = delta[(size_t)mtok * 1024 + w * 256 + d];
      else              val = v[(((size_t)(b * NH + w)) * Ls + l) * 256 + d];
      s += val; s2 = fmaf(val, val, s2);
    }
#pragma unroll
    for (int off = 32; off; off >>= 1) {
      s += __shfl_down(s, off);
      s2 += __shfl_down(s2, off);
    }
    if (lane == 0) {
      float mean = s * (1.f / 256.f);
      float var = s2 * (1.f / 256.f) - mean * mean;
      gin[(size_t)mtok * 1056 + 1024 + br * 8 + w] = f2bf(mean);
      gin[(size_t)mtok * 1056 + 1024 + br * 8 + 4 + w] = f2bf(sqrtf(fmaxf(var, 1e-6f)));
    }
  }
}

// ------- logits -> gates (bf16 hidden input) -------------------------------
__global__ __launch_bounds__(256) void mlp2_gates(
    const ushort_t* __restrict__ mh, const float* __restrict__ W2,
    const float* __restrict__ b2, const float* __restrict__ glt,
    float* __restrict__ gates)
{
  int mtok = blockIdx.x, t = threadIdx.x;
  float p[16];
#pragma unroll
  for (int j = 0; j < 16; ++j) p[j] = 0.f;
  for (int k = t; k < 2048; k += 256) {
    float hv = bf2f(mh[(size_t)mtok * 2048 + k]);
    const float* wr = W2 + (size_t)k * 16;
#pragma unroll
    for (int j4 = 0; j4 < 4; ++j4) {
      float4 w4 = *(const float4*)(wr + j4 * 4);
      p[j4*4+0] = fmaf(hv, w4.x, p[j4*4+0]);
      p[j4*4+1] = fmaf(hv, w4.y, p[j4*4+1]);
      p[j4*4+2] = fmaf(hv, w4.z, p[j4*4+2]);
      p[j4*4+3] = fmaf(hv, w4.w, p[j4*4+3]);
    }
  }
#pragma unroll
  for (int j = 0; j < 16; ++j)
#pragma unroll
    for (int off = 32; off; off >>= 1) p[j] += __shfl_down(p[j], off);
  __shared__ float red[4][16];
  __shared__ float zl[16];
  int w = t >> 6;
  if ((t & 63) == 0) {
#pragma unroll
    for (int j = 0; j < 16; ++j) red[w][j] = p[j];
  }
  __syncthreads();
  if (t < 16) {
    float tot = red[0][t] + red[1][t] + red[2][t] + red[3][t] + b2[t];
    float tempv = log1pf(expf(glt[t >> 2])) + 1e-4f;
    zl[t] = tot / tempv;
  }
  __syncthreads();
  if (t < 4) {
    float z0 = zl[t*4], z1 = zl[t*4+1], z2 = zl[t*4+2], z3 = zl[t*4+3];
    float mx = fmaxf(fmaxf(z0, z1), fmaxf(z2, z3));
    float e0 = expf(z0 - mx), e1 = expf(z1 - mx), e2 = expf(z2 - mx), e3 = expf(z3 - mx);
    float inv = 1.f / (e0 + e1 + e2 + e3);
    gates[(size_t)mtok * 16 + t * 4 + 0] = e0 * inv;
    gates[(size_t)mtok * 16 + t * 4 + 1] = e1 * inv;
    gates[(size_t)mtok * 16 + t * 4 + 2] = e2 * inv;
    gates[(size_t)mtok * 16 + t * 4 + 3] = e3 * inv;
  }
}

// ------- o = gated mix, RMSNorm -> bf16 ------------------------------------
__global__ __launch_bounds__(256) void combine_norm_bf(
    const float* __restrict__ firs, const float* __restrict__ firl,
    const float* __restrict__ delta, const float* __restrict__ v,
    const float* __restrict__ gates, const float* __restrict__ onw,
    ushort_t* __restrict__ o)
{
  int mh = blockIdx.x;
  int mtok = mh >> 2, h = mh & 3;
  int t = threadIdx.x;
  int b = mtok >> 11, l = mtok & 2047;
  const float* g = gates + (size_t)mtok * 16 + h * 4;
  float w0 = g[0], w1 = g[1], w2 = g[2], w3 = g[3];
  size_t tb = (size_t)mtok * 1024 + h * 256 + t;
  float val = w0 * firs[tb] + w1 * firl[tb] + w2 * delta[tb]
            + w3 * v[(((size_t)(b * NH + h)) * Ls + l) * 256 + t];
  float s2 = val * val;
#pragma unroll
  for (int off = 32; off; off >>= 1) s2 += __shfl_down(s2, off);
  __shared__ float r4[4];
  if ((t & 63) == 0) r4[t >> 6] = s2;
  __syncthreads();
  float tot = r4[0] + r4[1] + r4[2] + r4[3];
  float rms = rsqrtf(tot * (1.f / 256.f) + 1e-5f);
  o[tb] = f2bf(val * rms * onw[t]);
}

// ---------------------------------------------------------------------------
extern "C" void kernel_launch(void* const* d_in, const int* in_sizes, int n_in,
                              void* d_out, int out_size, void* d_ws, size_t ws_size,
                              hipStream_t stream) {
  const float* x     = (const float*)d_in[0];
  const float* Wq    = (const float*)d_in[1];
  const float* Wk    = (const float*)d_in[2];
  const float* Wv    = (const float*)d_in[3];
  const float* Wb    = (const float*)d_in[4];
  const float* convq = (const float*)d_in[5];
  const float* convk = (const float*)d_in[6];
  const float* convv = (const float*)d_in[7];
  const float* firsw = (const float*)d_in[8];
  const float* firlw = (const float*)d_in[9];
  const float* mlpw1 = (const float*)d_in[10];
  const float* mlpb1 = (const float*)d_in[11];
  const float* mlpw2 = (const float*)d_in[12];
  const float* mlpb2 = (const float*)d_in[13];
  const float* glt   = (const float*)d_in[14];
  const float* onw   = (const float*)d_in[15];
  const float* Wo    = (const float*)d_in[16];
  float* ws = (float*)d_ws;

  ushort_t* x_bf   = (ushort_t*)(ws + off_firs);
  ushort_t* Wqkv_t = (ushort_t*)(ws + off_firl);  // 3 x [1024][1024] contiguous
  ushort_t* gin_bf = (ushort_t*)(ws + off_gin);
  ushort_t* w1_t   = (ushort_t*)(ws + off_k);     // kn dead after chunk_prep
  ushort_t* o_bf   = (ushort_t*)(ws + off_xv);
  ushort_t* Wo_t   = (ushort_t*)(ws + off_beta);  // spans into attn (dead)
  ushort_t* mlph_bf= (ushort_t*)(ws + off_mlph);
  ushort_t* wn_bf  = (ushort_t*)(ws + off_firs);
  ushort_t* q_bf   = (ushort_t*)(ws + off_firs + 2097152);
  ushort_t* knT_bf = (ushort_t*)(ws + off_firl);
  float* x3   = ws + off_xq;     // fused [4096][3072] spans xq/xk/xv
  float* kb_f = ws + off_gin;
  float* vb_f = ws + off_mlph;
  float* firs_f = ws + off_xq;   // x3 dead after conv_prep
  float* firl_f = ws + off_xk;

  dim3 blk(256);
  // fused q/k/v projection (one N=3072 GEMM) + beta
  to_bf16<<<2048, blk, 0, stream>>>(x, x_bf, 4194304);
  convT<<<dim3(32, 32), blk, 0, stream>>>(Wq, Wqkv_t, 1024, 1024);
  convT<<<dim3(32, 32), blk, 0, stream>>>(Wk, Wqkv_t + 1048576, 1024, 1024);
  convT<<<dim3(32, 32), blk, 0, stream>>>(Wv, Wqkv_t + 2097152, 1024, 1024);
  gemm_bf16<<<dim3(24, 32), blk, 0, stream>>>(x_bf, Wqkv_t, x3, 3072, 1024, nullptr, 0, 0);
  beta_sigmoid<<<4096, blk, 0, stream>>>(x, Wb, ws + off_beta);
  // fused conv4+silu + l2norm + beta products
  conv_prep<<<16384, blk, 0, stream>>>(x3, convq, convk, convv, ws + off_beta,
                                       ws + off_q, ws + off_k, kb_f, vb_f, ws + off_v);
  // per-chunk T inverse, attn, u (->xv), bf16 {-w, q, knT}
  chunk_prep<<<512, blk, 0, stream>>>(kb_f, ws + off_k, ws + off_q, vb_f,
                                      ws + off_attn, ws + off_xv, wn_bf, q_bf, knT_bf);
  // merged serial MFMA scan (delta -> off_q) + FIR (firs/firl -> x3 regions)
  delta_fir<<<2176, blk, 0, stream>>>(wn_bf, q_bf, knT_bf, ws + off_attn,
                                      ws + off_xv, ws + off_q,
                                      ws + off_v, firlw, firsw, firl_f, firs_f);
  // gate input (bf16), MLP1 (MFMA, gelu, bf16 out), gates
  build_gate_in_bf<<<4096, blk, 0, stream>>>(x, firs_f, firl_f, ws + off_q,
                                             ws + off_v, gin_bf);
  convT<<<dim3(64, 33), blk, 0, stream>>>(mlpw1, w1_t, 1056, 2048);
  gemm_bf16<<<dim3(16, 32), blk, 0, stream>>>(gin_bf, w1_t, (float*)mlph_bf,
                                              2048, 1056, mlpb1, 1, 1);
  mlp2_gates<<<4096, blk, 0, stream>>>(mlph_bf, mlpw2, mlpb2, glt, ws + off_gates);
  // combine + RMSNorm -> bf16, output projection (MFMA)
  combine_norm_bf<<<16384, blk, 0, stream>>>(firs_f, firl_f, ws + off_q,
                                             ws + off_v, ws + off_gates, onw, o_bf);
  convT<<<dim3(32, 32), blk, 0, stream>>>(Wo, Wo_t, 1024, 1024);
  gemm_bf16<<<dim3(8, 32), blk, 0, stream>>>(o_bf, Wo_t, (float*)d_out, 1024, 1024, nullptr, 0, 0);
}